// Round 16
// baseline (140.012 us; speedup 1.0000x reference)
//
#include <hip/hip_runtime.h>

// Problem constants
#define NB 8
#define NS 256
#define ND 64
#define NV 8192
#define CH 32       // R16: s-chunk doubled -> 1152 streams x 512 KB
#define NCHUNK 1152 // sum over t of (t/32 + 1)

typedef float f32x4 __attribute__((ext_vector_type(4)));
typedef short s16x4 __attribute__((ext_vector_type(4)));
typedef short s16x8 __attribute__((ext_vector_type(8)));
typedef unsigned short u16;
typedef u16 u16x4 __attribute__((ext_vector_type(4)));
typedef u16 u16x8 __attribute__((ext_vector_type(8)));

__device__ __forceinline__ short f2bf(float x) {
    union { float f; unsigned u; } v; v.f = x;
    unsigned u = v.u + 0x7FFFu + ((v.u >> 16) & 1u);  // RNE
    return (short)(u >> 16);
}

__device__ __forceinline__ float bf2f(u16 v) {
    union { unsigned u; float f; } q; q.u = ((unsigned)v) << 16; return q.f;
}

__device__ __forceinline__ s16x8 cvt8(f32x4 lo, f32x4 hi) {
    s16x8 r;
    r[0] = f2bf(lo.x); r[1] = f2bf(lo.y); r[2] = f2bf(lo.z); r[3] = f2bf(lo.w);
    r[4] = f2bf(hi.x); r[5] = f2bf(hi.y); r[6] = f2bf(hi.z); r[7] = f2bf(hi.w);
    return r;
}

__device__ __forceinline__ f32x4 ntld(const float* p) {
    return __builtin_nontemporal_load(reinterpret_cast<const f32x4*>(p));
}

__device__ __forceinline__ f32x4 shfl_xor4(f32x4 v, int mask) {
    f32x4 r;
    r.x = __shfl_xor(v.x, mask, 64);
    r.y = __shfl_xor(v.y, mask, 64);
    r.z = __shfl_xor(v.z, mask, 64);
    r.w = __shfl_xor(v.w, mask, 64);
    return r;
}

// hb16[b,s,d] = bf16(embed[x[b,s], d]); y = 0; eb = bf16(embed)  (512 blocks)
__global__ __launch_bounds__(256) void k_init(const int* __restrict__ x,
                                              const float* __restrict__ embed,
                                              u16* __restrict__ hb16,
                                              float* __restrict__ y,
                                              short* __restrict__ eb) {
    int tid = blockIdx.x * 256 + threadIdx.x;
    int bs = tid >> 6;
    int d  = tid & 63;
    hb16[tid] = (u16)f2bf(embed[(size_t)x[bs] * ND + d]);
    y[tid] = 0.f;
    f32x4 v = *reinterpret_cast<const f32x4*>(embed + (size_t)tid * 4);
    s16x4 o;
    o.x = f2bf(v.x); o.y = f2bf(v.y); o.z = f2bf(v.z); o.w = f2bf(v.w);
    *reinterpret_cast<s16x4*>(eb + (size_t)tid * 4) = o;
}

// y[b,t,o] += sum_{s in chunk, s<=t} sum_d h[b,s,d] * K[t,s,d,o]
// Triangular LJF; nt K-stream; 2-deep hoisted prefetch; bf16 h-stage (32 KB);
// shfl-xor pre-reduction. R16: CH=32 (fewer, longer K streams).
__global__ __launch_bounds__(256) void k_bilinear(const u16* __restrict__ hb,
                                                  const float* __restrict__ K,
                                                  float* __restrict__ y) {
    int L = (NCHUNK - 1) - (int)blockIdx.x;
    int g = 0;
    while (16 * (g + 1) * (g + 2) <= L) g++;      // group g = t>>5
    int rem = L - 16 * g * (g + 1);
    int tq  = rem / (g + 1);
    int t   = 32 * g + tq;
    int c   = rem - tq * (g + 1);
    int s0  = c * CH;
    int ns  = min(t + 1 - s0, CH);

    int ot = threadIdx.x & 15;   // o-quad index
    int dg = threadIdx.x >> 4;   // d-group 0..15
    int o4 = ot * 4;
    int db = dg * 4;

    // K prefetch first (no smem dependency): 2 slices in flight
    const float* Kp = K + (size_t)t * NS * ND * ND + (size_t)s0 * ND * ND
                        + db * ND + o4;
    f32x4 a0 = ntld(Kp);
    f32x4 a1 = ntld(Kp + ND);
    f32x4 a2 = ntld(Kp + 2 * ND);
    f32x4 a3 = ntld(Kp + 3 * ND);
    f32x4 b0 = a0, b1 = a1, b2 = a2, b3 = a3;
    if (ns > 1) {
        const float* K1 = Kp + (ND * ND);
        b0 = ntld(K1);
        b1 = ntld(K1 + ND);
        b2 = ntld(K1 + 2 * ND);
        b3 = ntld(K1 + 3 * ND);
    }

    __shared__ __align__(16) u16 smemh[NB * CH * ND]; // 32 KB; red reuses 8 KB

    // stage bf16 h tile: (NB*CH*ND/8) x 16B chunks
    for (int j = threadIdx.x; j < (NB * CH * ND) / 8; j += 256) {
        int b  = j >> 8;          // / (CH*ND/8) = /256
        int r8 = j & 255;
        *reinterpret_cast<u16x8*>(smemh + j * 8) =
            *reinterpret_cast<const u16x8*>(hb + (size_t)b * NS * ND
                                               + (size_t)s0 * ND + r8 * 8);
    }
    __syncthreads();

    f32x4 acc[NB];
#pragma unroll
    for (int b = 0; b < NB; b++) acc[b] = (f32x4)(0.f);

    for (int si = 0; si < ns; si++) {
        f32x4 m0 = b0, m1 = b1, m2 = b2, m3 = b3;
        if (si + 2 < ns) {
            const float* Kn = Kp + (size_t)(si + 2) * (ND * ND);
            m0 = ntld(Kn);
            m1 = ntld(Kn + ND);
            m2 = ntld(Kn + 2 * ND);
            m3 = ntld(Kn + 3 * ND);
        }
#pragma unroll
        for (int b = 0; b < NB; b++) {
            u16x4 hv = *reinterpret_cast<const u16x4*>(
                smemh + b * (CH * ND) + si * ND + db);
            acc[b] += bf2f(hv[0]) * a0;
            acc[b] += bf2f(hv[1]) * a1;
            acc[b] += bf2f(hv[2]) * a2;
            acc[b] += bf2f(hv[3]) * a3;
        }
        a0 = b0; a1 = b1; a2 = b2; a3 = b3;
        b0 = m0; b1 = m1; b2 = m2; b3 = m3;
    }

    // in-wave reduction over the wave's 4 d-groups (lanes ^16, ^32 share ot)
#pragma unroll
    for (int b = 0; b < NB; b++) {
        acc[b] += shfl_xor4(acc[b], 16);
        acc[b] += shfl_xor4(acc[b], 32);
    }
    __syncthreads();   // stage no longer needed; reuse as reduction scratch

    int wave = threadIdx.x >> 6;
    int lane = threadIdx.x & 63;
    f32x4* red = reinterpret_cast<f32x4*>(smemh); // 4 waves x 8 b x 16 ot = 8 KB
    if (lane < 16) {
#pragma unroll
        for (int b = 0; b < NB; b++) red[(wave * NB + b) * 16 + lane] = acc[b];
    }
    __syncthreads();

    if (threadIdx.x < 128) {
        int b = threadIdx.x >> 4;
        int o = threadIdx.x & 15;
        f32x4 s = (f32x4)(0.f);
#pragma unroll
        for (int w = 0; w < 4; w++)
            s += red[(w * NB + b) * 16 + o];
        float* yp = y + ((size_t)b * NS + t) * ND + o * 4;
        atomicAdd(yp + 0, s.x);
        atomicAdd(yp + 1, s.y);
        atomicAdd(yp + 2, s.z);
        atomicAdd(yp + 3, s.w);
    }
}

// out[bt, v] = sum_o y[bt, o] * E[v, o]  via bf16 MFMA (16x16x32, K=o)
__global__ __launch_bounds__(256) void k_logits_mfma(const float* __restrict__ y,
                                                     const short* __restrict__ eb,
                                                     float* __restrict__ out) {
    int bt0  = blockIdx.x * 16;
    int wave = threadIdx.x >> 6;
    int lane = threadIdx.x & 63;
    int m    = lane & 15;      // A row / B col / D col
    int kg   = lane >> 4;      // k-group of 8
    int vb0  = blockIdx.y * 1024 + wave * 256;

    const float* yrow = y + (size_t)(bt0 + m) * ND + kg * 8;
    f32x4 p0 = *reinterpret_cast<const f32x4*>(yrow);
    f32x4 p1 = *reinterpret_cast<const f32x4*>(yrow + 4);
    f32x4 p2 = *reinterpret_cast<const f32x4*>(yrow + 32);
    f32x4 p3 = *reinterpret_cast<const f32x4*>(yrow + 36);
    s16x8 a0 = cvt8(p0, p1);
    s16x8 a1 = cvt8(p2, p3);

    for (int nt = 0; nt < 16; nt++) {
        int v0 = vb0 + nt * 16;
        const short* erow = eb + (size_t)(v0 + m) * ND + kg * 8;
        s16x8 b0 = *reinterpret_cast<const s16x8*>(erow);
        s16x8 b1 = *reinterpret_cast<const s16x8*>(erow + 32);
        f32x4 cacc = (f32x4)(0.f);
        cacc = __builtin_amdgcn_mfma_f32_16x16x32_bf16(a0, b0, cacc, 0, 0, 0);
        cacc = __builtin_amdgcn_mfma_f32_16x16x32_bf16(a1, b1, cacc, 0, 0, 0);
        float* op = out + (size_t)(bt0 + kg * 4) * NV + v0 + m;
#pragma unroll
        for (int r = 0; r < 4; r++)
            __builtin_nontemporal_store(cacc[r], op + (size_t)r * NV);
    }
}

extern "C" void kernel_launch(void* const* d_in, const int* in_sizes, int n_in,
                              void* d_out, int out_size, void* d_ws, size_t ws_size,
                              hipStream_t stream) {
    const int*   x     = (const int*)d_in[0];
    const float* embed = (const float*)d_in[1];
    const float* K     = (const float*)d_in[2];
    float* out = (float*)d_out;

    float* y   = (float*)d_ws;                // 131072 f32 (512 KB)
    short* eb  = (short*)(y + NB * NS * ND);  // 524288 bf16 (1 MB)
    u16*   hbf = (u16*)(eb + (size_t)NV * ND); // 131072 bf16 (256 KB)

    k_init<<<dim3(512), 256, 0, stream>>>(x, embed, hbf, y, eb);
    k_bilinear<<<dim3(NCHUNK), 256, 0, stream>>>(hbf, K, y);
    k_logits_mfma<<<dim3((NB * NS) / 16, NV / 1024), 256, 0, stream>>>(y, eb, out);
}

// Round 17
// 136.834 us; speedup vs baseline: 1.0232x; 1.0232x over previous
//
#include <hip/hip_runtime.h>

// Problem constants
#define NB 8
#define NS 256
#define ND 64
#define NV 8192
#define CH 16       // s-chunk per bilinear block (proven optimum: 8=153.6, 16=137.0, 32=140.0)
#define NCHUNK 2176 // sum over t of (t/16 + 1)

typedef float f32x4 __attribute__((ext_vector_type(4)));
typedef short s16x4 __attribute__((ext_vector_type(4)));
typedef short s16x8 __attribute__((ext_vector_type(8)));

__device__ __forceinline__ short f2bf(float x) {
    union { float f; unsigned u; } v; v.f = x;
    unsigned u = v.u + 0x7FFFu + ((v.u >> 16) & 1u);  // RNE
    return (short)(u >> 16);
}

__device__ __forceinline__ s16x8 cvt8(f32x4 lo, f32x4 hi) {
    s16x8 r;
    r[0] = f2bf(lo.x); r[1] = f2bf(lo.y); r[2] = f2bf(lo.z); r[3] = f2bf(lo.w);
    r[4] = f2bf(hi.x); r[5] = f2bf(hi.y); r[6] = f2bf(hi.z); r[7] = f2bf(hi.w);
    return r;
}

__device__ __forceinline__ f32x4 ntld(const float* p) {
    return __builtin_nontemporal_load(reinterpret_cast<const f32x4*>(p));
}

// h[b,s,d] = embed[x[b,s], d]; y = 0; eb = bf16(embed)   (512 blocks)
__global__ __launch_bounds__(256) void k_init(const int* __restrict__ x,
                                              const float* __restrict__ embed,
                                              float* __restrict__ h,
                                              float* __restrict__ y,
                                              short* __restrict__ eb) {
    int tid = blockIdx.x * 256 + threadIdx.x;
    int bs = tid >> 6;
    int d  = tid & 63;
    h[tid] = embed[(size_t)x[bs] * ND + d];
    y[tid] = 0.f;
    f32x4 v = *reinterpret_cast<const f32x4*>(embed + (size_t)tid * 4);
    s16x4 o;
    o.x = f2bf(v.x); o.y = f2bf(v.y); o.z = f2bf(v.z); o.w = f2bf(v.w);
    *reinterpret_cast<s16x4*>(eb + (size_t)tid * 4) = o;
}

// y[b,t,o] += sum_{s in chunk, s<=t} sum_d h[b,s,d] * K[t,s,d,o]
// Triangular LJF launch; CH=16; nt K-stream; 2-deep register prefetch,
// prefetch hoisted above the h-stage. (R14-proven best = 137.0 us)
__global__ __launch_bounds__(256) void k_bilinear(const float* __restrict__ h,
                                                  const float* __restrict__ K,
                                                  float* __restrict__ y) {
    int L = (NCHUNK - 1) - (int)blockIdx.x;
    int g = 0;
    while (8 * (g + 1) * (g + 2) <= L) g++;       // group g = t>>4
    int rem = L - 8 * g * (g + 1);
    int tq  = rem / (g + 1);
    int t   = 16 * g + tq;
    int c   = rem - tq * (g + 1);
    int s0  = c * CH;
    int ns  = min(t + 1 - s0, CH);

    int ot = threadIdx.x & 15;   // o-quad index
    int dg = threadIdx.x >> 4;   // d-group 0..15
    int o4 = ot * 4;
    int db = dg * 4;

    // K prefetch first (no smem dependency): 2 slices in flight
    const float* Kp = K + (size_t)t * NS * ND * ND + (size_t)s0 * ND * ND
                        + db * ND + o4;
    f32x4 a0 = ntld(Kp);
    f32x4 a1 = ntld(Kp + ND);
    f32x4 a2 = ntld(Kp + 2 * ND);
    f32x4 a3 = ntld(Kp + 3 * ND);
    f32x4 b0 = a0, b1 = a1, b2 = a2, b3 = a3;
    if (ns > 1) {
        const float* K1 = Kp + (ND * ND);
        b0 = ntld(K1);
        b1 = ntld(K1 + ND);
        b2 = ntld(K1 + 2 * ND);
        b3 = ntld(K1 + 3 * ND);
    }

    __shared__ float smem[NB * CH * ND]; // 32 KB; reused for reduction

    for (int i = threadIdx.x; i < NB * CH * ND; i += 256) {
        int b    = i >> 10;
        int rem2 = i & 1023;
        smem[i] = h[((size_t)b * NS + s0) * ND + rem2];
    }
    __syncthreads();

    f32x4 acc[NB];
#pragma unroll
    for (int b = 0; b < NB; b++) acc[b] = (f32x4)(0.f);

    for (int si = 0; si < ns; si++) {
        f32x4 m0 = b0, m1 = b1, m2 = b2, m3 = b3;
        if (si + 2 < ns) {
            const float* Kn = Kp + (size_t)(si + 2) * (ND * ND);
            m0 = ntld(Kn);
            m1 = ntld(Kn + ND);
            m2 = ntld(Kn + 2 * ND);
            m3 = ntld(Kn + 3 * ND);
        }
#pragma unroll
        for (int b = 0; b < NB; b++) {
            const float* hb = smem + b * (CH * ND) + si * ND + db;
            acc[b] += hb[0] * a0;
            acc[b] += hb[1] * a1;
            acc[b] += hb[2] * a2;
            acc[b] += hb[3] * a3;
        }
        a0 = b0; a1 = b1; a2 = b2; a3 = b3;
        b0 = m0; b1 = m1; b2 = m2; b3 = m3;
    }
    __syncthreads();

    f32x4* red = reinterpret_cast<f32x4*>(smem);
#pragma unroll
    for (int b = 0; b < NB; b++) red[(dg * NB + b) * 16 + ot] = acc[b];
    __syncthreads();

    if (threadIdx.x < 128) {
        int b = threadIdx.x >> 4;
        int o = threadIdx.x & 15;
        f32x4 s = (f32x4)(0.f);
#pragma unroll
        for (int gg = 0; gg < 16; gg++)
            s += red[(gg * NB + b) * 16 + o];
        float* yp = y + ((size_t)b * NS + t) * ND + o * 4;
        atomicAdd(yp + 0, s.x);
        atomicAdd(yp + 1, s.y);
        atomicAdd(yp + 2, s.z);
        atomicAdd(yp + 3, s.w);
    }
}

// out[bt, v] = sum_o y[bt, o] * E[v, o]  via bf16 MFMA (16x16x32, K=o)
__global__ __launch_bounds__(256) void k_logits_mfma(const float* __restrict__ y,
                                                     const short* __restrict__ eb,
                                                     float* __restrict__ out) {
    int bt0  = blockIdx.x * 16;
    int wave = threadIdx.x >> 6;
    int lane = threadIdx.x & 63;
    int m    = lane & 15;      // A row / B col / D col
    int kg   = lane >> 4;      // k-group of 8
    int vb0  = blockIdx.y * 1024 + wave * 256;

    const float* yrow = y + (size_t)(bt0 + m) * ND + kg * 8;
    f32x4 p0 = *reinterpret_cast<const f32x4*>(yrow);
    f32x4 p1 = *reinterpret_cast<const f32x4*>(yrow + 4);
    f32x4 p2 = *reinterpret_cast<const f32x4*>(yrow + 32);
    f32x4 p3 = *reinterpret_cast<const f32x4*>(yrow + 36);
    s16x8 a0 = cvt8(p0, p1);
    s16x8 a1 = cvt8(p2, p3);

    for (int nt = 0; nt < 16; nt++) {
        int v0 = vb0 + nt * 16;
        const short* erow = eb + (size_t)(v0 + m) * ND + kg * 8;
        s16x8 b0 = *reinterpret_cast<const s16x8*>(erow);
        s16x8 b1 = *reinterpret_cast<const s16x8*>(erow + 32);
        f32x4 cacc = (f32x4)(0.f);
        cacc = __builtin_amdgcn_mfma_f32_16x16x32_bf16(a0, b0, cacc, 0, 0, 0);
        cacc = __builtin_amdgcn_mfma_f32_16x16x32_bf16(a1, b1, cacc, 0, 0, 0);
        float* op = out + (size_t)(bt0 + kg * 4) * NV + v0 + m;
#pragma unroll
        for (int r = 0; r < 4; r++)
            __builtin_nontemporal_store(cacc[r], op + (size_t)r * NV);
    }
}

extern "C" void kernel_launch(void* const* d_in, const int* in_sizes, int n_in,
                              void* d_out, int out_size, void* d_ws, size_t ws_size,
                              hipStream_t stream) {
    const int*   x     = (const int*)d_in[0];
    const float* embed = (const float*)d_in[1];
    const float* K     = (const float*)d_in[2];
    float* out = (float*)d_out;

    float* h  = (float*)d_ws;               // 131072 f32 (512 KB)
    float* y  = h + NB * NS * ND;           // 131072 f32 (512 KB)
    short* eb = (short*)(y + NB * NS * ND); // 524288 bf16 (1 MB)

    k_init<<<dim3(512), 256, 0, stream>>>(x, embed, h, y, eb);
    k_bilinear<<<dim3(NCHUNK), 256, 0, stream>>>(h, K, y);
    k_logits_mfma<<<dim3((NB * NS) / 16, NV / 1024), 256, 0, stream>>>(y, eb, out);
}